// Round 1
// baseline (130.825 us; speedup 1.0000x reference)
//
#include <hip/hip_runtime.h>
#include <hip/hip_bf16.h>
#include <math.h>

typedef __bf16 bf16x8 __attribute__((ext_vector_type(8)));
typedef float  f32x4  __attribute__((ext_vector_type(4)));
typedef unsigned short u16x8 __attribute__((ext_vector_type(8)));

#define B_      16
#define LIN_    32768
#define LOUT_   32760
#define CIN_    21
#define CPAD_   24      // pad channels 21->24 so each row is 48B (16B aligned)
#define KT_     9
#define F_      128
#define KSTEPS_ 7       // R = 9*24 = 216, padded to 224 = 7 * 32
#define BL_     64      // l-positions per sub-tile
#define SUBS_   4
#define TILE_L_ 256     // l-positions per block
#define ROWS_   73      // staged input rows per sub-tile (64 + 9)
#define NTILE_  128     // ceil(32760 / 256)

__device__ __forceinline__ unsigned short f2bf(float f) {
  unsigned u = __float_as_uint(f);
  u += 0x7FFFu + ((u >> 16) & 1u);   // round-to-nearest-even
  return (unsigned short)(u >> 16);
}
__device__ __forceinline__ float bf2f(unsigned short h) {
  return __uint_as_float(((unsigned)h) << 16);
}

__global__ __launch_bounds__(256, 4)
void ckn1d_mfma(const float* __restrict__ X, const float* __restrict__ W,
                const float* __restrict__ scale_p, const float* __restrict__ bias_p,
                float* __restrict__ Y)
{
  // im2col trick: patch for row l = 224 contiguous shorts starting at l*CPAD_
  __shared__ __align__(16) unsigned short tileA[ROWS_ * CPAD_]; // 3504 B
  __shared__ float rowsq[ROWS_];
  __shared__ float inv_s[BL_];

  const int tid  = threadIdx.x;
  const int wv   = tid >> 6;       // wave 0..3 -> filter group
  const int lane = tid & 63;
  const int la   = lane & 15;
  const int q    = lane >> 4;

  const int bx   = blockIdx.x;
  const int b    = bx >> 7;
  const int tile = bx & (NTILE_ - 1);
  const int l0t  = tile * TILE_L_;

  const float scale = scale_p[0];
  const int f0 = wv * 32 + la;
  const float bias0 = bias_p[f0];
  const float bias1 = bias_p[f0 + 16];

  // ---- B fragments in registers (bf16, zero-padded), once per block ----
  // B[r][f]: lane holds k-chunk r = t*32 + q*8 + j, col f = f0 (+16 for nf=1)
  u16x8 bw[KSTEPS_][2];
  #pragma unroll
  for (int t = 0; t < KSTEPS_; ++t) {
    #pragma unroll
    for (int nf = 0; nf < 2; ++nf) {
      #pragma unroll
      for (int j = 0; j < 8; ++j) {
        int r = t * 32 + q * 8 + j;
        int k = r / CPAD_;
        int c = r - k * CPAD_;
        float v = 0.f;
        if (c < CIN_ && k < KT_) v = W[(k * CIN_ + c) * F_ + f0 + nf * 16];
        bw[t][nf][j] = f2bf(v);
      }
    }
  }

  const float* __restrict__ Xb = X + (size_t)b * LIN_ * CIN_;
  float*       __restrict__ Yb = Y + (size_t)b * LOUT_ * F_;

  const f32x4 fzero = {0.f, 0.f, 0.f, 0.f};

  for (int sub = 0; sub < SUBS_; ++sub) {
    const int l0 = l0t + sub * BL_;
    __syncthreads();  // protect LDS reuse vs previous iteration's readers

    // zero the pad columns c = 21..23 for all rows (keeps NaN out of MFMA)
    if (tid < ROWS_ * 3) {
      int r = tid / 3;
      int c = CIN_ + (tid - r * 3);
      tileA[r * CPAD_ + c] = 0;
    }
    // stage ROWS_*CIN_ = 1533 contiguous floats -> bf16 LDS (clamp tail to 0)
    {
      const float* src = Xb + (size_t)l0 * CIN_;
      for (int i = tid; i < ROWS_ * CIN_; i += 256) {
        int r = i / CIN_;
        int c = i - r * CIN_;
        float v = ((l0 + r) < LIN_) ? src[i] : 0.f;
        tileA[r * CPAD_ + c] = f2bf(v);
      }
    }
    __syncthreads();

    // per-row sum of squares (pad cols are zero, so sum all 24)
    if (tid < 72) {
      const u16x8* rp = (const u16x8*)&tileA[tid * CPAD_];
      float s = 0.f;
      #pragma unroll
      for (int g = 0; g < 3; ++g) {
        u16x8 v = rp[g];
        #pragma unroll
        for (int j = 0; j < 8; ++j) { float x = bf2f(v[j]); s += x * x; }
      }
      rowsq[tid] = s;
    }
    __syncthreads();

    // sliding 9-row energy -> fused scale/(sqrt(e+eps)+eps)
    if (tid < BL_) {
      float e = 0.f;
      #pragma unroll
      for (int t = 0; t < KT_; ++t) e += rowsq[tid + t];
      inv_s[tid] = scale / (sqrtf(e + 1e-5f) + 1e-5f);
    }

    // ---- MFMA main loop: 4 m-frags x 2 n-frags, 7 K-steps ----
    f32x4 acc[4][2];
    #pragma unroll
    for (int m = 0; m < 4; ++m) { acc[m][0] = fzero; acc[m][1] = fzero; }

    #pragma unroll
    for (int t = 0; t < KSTEPS_; ++t) {
      #pragma unroll
      for (int m = 0; m < 4; ++m) {
        // A[l][r]: row = m*16+la, elems r = t*32 + q*8 + 0..7 (contig 16B)
        bf16x8 a = *(const bf16x8*)&tileA[(m * 16 + la) * CPAD_ + t * 32 + q * 8];
        acc[m][0] = __builtin_amdgcn_mfma_f32_16x16x32_bf16(
            a, __builtin_bit_cast(bf16x8, bw[t][0]), acc[m][0], 0, 0, 0);
        acc[m][1] = __builtin_amdgcn_mfma_f32_16x16x32_bf16(
            a, __builtin_bit_cast(bf16x8, bw[t][1]), acc[m][1], 0, 0, 0);
      }
    }
    __syncthreads();  // inv_s ready for everyone

    // ---- epilogue: C/D layout col=lane&15, row=(lane>>4)*4+reg ----
    #pragma unroll
    for (int m = 0; m < 4; ++m) {
      #pragma unroll
      for (int rg = 0; rg < 4; ++rg) {
        int lloc = m * 16 + q * 4 + rg;
        int lg = l0 + lloc;
        if (lg < LOUT_) {
          float iv = inv_s[lloc];
          float* yo = Yb + (size_t)lg * F_ + f0;
          yo[0]  = acc[m][0][rg] * iv + bias0;
          yo[16] = acc[m][1][rg] * iv + bias1;
        }
      }
    }
  }
}

extern "C" void kernel_launch(void* const* d_in, const int* in_sizes, int n_in,
                              void* d_out, int out_size, void* d_ws, size_t ws_size,
                              hipStream_t stream) {
  const float* X  = (const float*)d_in[0];
  const float* W  = (const float*)d_in[1];
  const float* S  = (const float*)d_in[2];
  const float* Bi = (const float*)d_in[3];
  float* Y = (float*)d_out;
  dim3 grid(B_ * NTILE_), block(256);
  ckn1d_mfma<<<grid, block, 0, stream>>>(X, W, S, Bi, Y);
}

// Round 2
// 83.144 us; speedup vs baseline: 1.5735x; 1.5735x over previous
//
#include <hip/hip_runtime.h>
#include <hip/hip_bf16.h>
#include <math.h>

typedef __bf16 bf16x8 __attribute__((ext_vector_type(8)));
typedef float  f32x4  __attribute__((ext_vector_type(4)));
typedef unsigned short u16x8 __attribute__((ext_vector_type(8)));

#define B_      16
#define LIN_    32768
#define LOUT_   32760
#define CIN_    21
#define CPAD_   24      // channels padded 21->24: row = 48B, 16B-aligned
#define KT_     9
#define F_      128
#define KSTEPS_ 7       // R = 9*24 = 216, padded to 224 = 7*32
#define TILE_L_ 256     // output rows per block
#define ROWS_   264     // staged rows: 256 + 8 (window overlap)
#define ROWSA_  266     // + 2 zero rows so the r>=216 tail never reads junk
#define NTILE_  128     // 32760 / 256 (ceil)
#define OBST_   136     // outbuf row stride in dwords (544B = 34*16B, %32=8)

__device__ __forceinline__ unsigned short f2bf(float f) {
  unsigned u = __float_as_uint(f);
  u += 0x7FFFu + ((u >> 16) & 1u);   // RNE
  return (unsigned short)(u >> 16);
}
__device__ __forceinline__ float bf2f(unsigned short h) {
  return __uint_as_float(((unsigned)h) << 16);
}

__global__ __launch_bounds__(256, 3)
void ckn1d_mfma(const float* __restrict__ X, const float* __restrict__ W,
                const float* __restrict__ scale_p, const float* __restrict__ bias_p,
                float* __restrict__ Y)
{
  // im2col trick: patch for row l = 224 contiguous shorts starting at l*24
  __shared__ __align__(16) unsigned short tileA[ROWSA_ * CPAD_]; // 12768 B
  __shared__ float rowsq[ROWS_];                                 //  1056 B
  __shared__ float inv_s[TILE_L_];                               //  1024 B
  __shared__ __align__(16) float outbuf[64 * OBST_];             // 34816 B

  const int tid  = threadIdx.x;
  const int wv   = tid >> 6;       // wave -> filter group of 32
  const int lane = tid & 63;
  const int la   = lane & 15;
  const int q    = lane >> 4;

  const int bx   = blockIdx.x;
  const int b    = bx >> 7;
  const int tile = bx & (NTILE_ - 1);
  const int l0t  = tile * TILE_L_;

  const float scale = scale_p[0];
  const int f0 = wv * 32 + la;
  const float bias0 = bias_p[f0];
  const float bias1 = bias_p[f0 + 16];

  // ---- B fragments in registers (bf16, zero-padded); W is L2/L3-hot ----
  u16x8 bw[KSTEPS_][2];
  #pragma unroll
  for (int t = 0; t < KSTEPS_; ++t) {
    #pragma unroll
    for (int nf = 0; nf < 2; ++nf) {
      #pragma unroll
      for (int j = 0; j < 8; ++j) {
        int r = t * 32 + q * 8 + j;
        int k = r / CPAD_;
        int c = r - k * CPAD_;
        float v = 0.f;
        if (c < CIN_ && k < KT_) v = W[(k * CIN_ + c) * F_ + f0 + nf * 16];
        bw[t][nf][j] = f2bf(v);
      }
    }
  }

  const float* __restrict__ Xb = X + (size_t)b * LIN_ * CIN_;
  float*       __restrict__ Yb = Y + (size_t)b * LOUT_ * F_;

  // ---- stage the whole 264-row window once (float4-coalesced) ----
  // zero pad cols c=21..23 for all rows + the 2 guard rows entirely
  for (int i = tid; i < ROWSA_ * 3; i += 256) {
    int r = i / 3;
    tileA[r * CPAD_ + CIN_ + (i - r * 3)] = 0;
  }
  for (int i = tid; i < 2 * CIN_; i += 256) {
    int r = ROWS_ + i / CIN_;
    tileA[r * CPAD_ + (i % CIN_)] = 0;
  }
  {
    const float* src = Xb + (size_t)l0t * CIN_;
    const int nvalid = min(ROWS_ * CIN_, (LIN_ - l0t) * CIN_);
    const int n4v = nvalid >> 2;                  // 1386 (or 1344 last tile)
    const float4* src4 = (const float4*)src;
    for (int i4 = tid; i4 < (ROWS_ * CIN_) / 4; i4 += 256) {
      float4 v;
      if (i4 < n4v) v = src4[i4];
      else          v = make_float4(0.f, 0.f, 0.f, 0.f);
      int base = i4 * 4;
      #pragma unroll
      for (int e = 0; e < 4; ++e) {
        int idx = base + e;
        int r = idx / CIN_;
        int c = idx - r * CIN_;
        float x = (e == 0) ? v.x : (e == 1) ? v.y : (e == 2) ? v.z : v.w;
        tileA[r * CPAD_ + c] = f2bf(x);
      }
    }
  }
  __syncthreads();

  // ---- per-row sum of squares, once for all 264 rows ----
  for (int r = tid; r < ROWS_; r += 256) {
    const u16x8* rp = (const u16x8*)&tileA[r * CPAD_];
    float s = 0.f;
    #pragma unroll
    for (int g = 0; g < 3; ++g) {
      u16x8 v = rp[g];
      #pragma unroll
      for (int j = 0; j < 8; ++j) { float x = bf2f(v[j]); s += x * x; }
    }
    rowsq[r] = s;
  }
  __syncthreads();

  // ---- sliding 9-row energy -> scale/(sqrt(e+eps)+eps), all 256 rows ----
  {
    float e = 0.f;
    #pragma unroll
    for (int t = 0; t < KT_; ++t) e += rowsq[tid + t];
    inv_s[tid] = scale / (sqrtf(e + 1e-5f) + 1e-5f);
  }
  __syncthreads();

  const f32x4 fzero = {0.f, 0.f, 0.f, 0.f};

  for (int sub = 0; sub < 4; ++sub) {
    const int ls = sub * 64;

    // ---- MFMA: 4 m-frags x 2 n-frags x 7 K-steps ----
    f32x4 acc[4][2];
    #pragma unroll
    for (int m = 0; m < 4; ++m) { acc[m][0] = fzero; acc[m][1] = fzero; }

    #pragma unroll
    for (int t = 0; t < KSTEPS_; ++t) {
      #pragma unroll
      for (int m = 0; m < 4; ++m) {
        bf16x8 a = *(const bf16x8*)&tileA[(ls + m * 16 + la) * CPAD_ + t * 32 + q * 8];
        acc[m][0] = __builtin_amdgcn_mfma_f32_16x16x32_bf16(
            a, __builtin_bit_cast(bf16x8, bw[t][0]), acc[m][0], 0, 0, 0);
        acc[m][1] = __builtin_amdgcn_mfma_f32_16x16x32_bf16(
            a, __builtin_bit_cast(bf16x8, bw[t][1]), acc[m][1], 0, 0, 0);
      }
    }

    // ---- assemble scaled tile in LDS (full-line stores after) ----
    #pragma unroll
    for (int m = 0; m < 4; ++m) {
      #pragma unroll
      for (int rg = 0; rg < 4; ++rg) {
        int lrow = m * 16 + q * 4 + rg;       // 0..63
        float iv = inv_s[ls + lrow];
        outbuf[lrow * OBST_ + f0]      = acc[m][0][rg] * iv + bias0;
        outbuf[lrow * OBST_ + f0 + 16] = acc[m][1][rg] * iv + bias1;
      }
    }
    __syncthreads();

    // ---- store: contiguous float4, 2 full 512B rows per instruction ----
    {
      const int lg0 = l0t + ls;
      for (int i = tid; i < 64 * 32; i += 256) {
        int r  = i >> 5;
        int c4 = i & 31;
        int lg = lg0 + r;
        if (lg < LOUT_) {
          float4 v = *(const float4*)&outbuf[r * OBST_ + c4 * 4];
          *(float4*)&Yb[(size_t)lg * F_ + c4 * 4] = v;
        }
      }
    }
    __syncthreads();  // outbuf reusable next sub
  }
}

extern "C" void kernel_launch(void* const* d_in, const int* in_sizes, int n_in,
                              void* d_out, int out_size, void* d_ws, size_t ws_size,
                              hipStream_t stream) {
  const float* X  = (const float*)d_in[0];
  const float* W  = (const float*)d_in[1];
  const float* S  = (const float*)d_in[2];
  const float* Bi = (const float*)d_in[3];
  float* Y = (float*)d_out;
  dim3 grid(B_ * NTILE_), block(256);
  ckn1d_mfma<<<grid, block, 0, stream>>>(X, W, S, Bi, Y);
}